// Round 7
// baseline (165.715 us; speedup 1.0000x reference)
//
#include <hip/hip_runtime.h>
#include <hip/hip_cooperative_groups.h>
#include <math.h>

#define B     8
#define C     1024
#define M     8
#define HW    4096
#define EPS   1e-6f
#define GAIN  0.3f

#define TPB   512          // 8 waves
#define NCG   16           // channel groups (cg = tid/32)
#define CPG   64           // channels per group
#define CLDS  32           // channels/cg staged in LDS (rest in regs)
#define CREG  32
#define TILE  128          // hw per block
#define NTILE 32           // HW/TILE; grid = B*NTILE = 256

typedef float floatx4 __attribute__((ext_vector_type(4)));

// manual RNE f32->bf16 (finite inputs)
__device__ __forceinline__ unsigned f2bf(float f) {
    unsigned x; __builtin_memcpy(&x, &f, 4);
    return (x + 0x7fffu + ((x >> 16) & 1u)) >> 16;
}
__device__ __forceinline__ unsigned packbf(float a, float b) {
    return f2bf(a) | (f2bf(b) << 16);
}
__device__ __forceinline__ float bflo(unsigned u) {
    unsigned v = u << 16; float f; __builtin_memcpy(&f, &v, 4); return f;
}
__device__ __forceinline__ float bfhi(unsigned u) {
    unsigned v = u & 0xffff0000u; float f; __builtin_memcpy(&f, &v, 4); return f;
}

// ws layout: [gridDim.x][2] stat partials (su, sq) = 2 KB
__global__ __launch_bounds__(TPB, 2) void fused(const float* __restrict__ z,
                                                const float* __restrict__ Wd,
                                                float* __restrict__ out,
                                                float* __restrict__ ws) {
    // 151.6 KB LDS total -> 1 block/CU
    __shared__ __align__(16) unsigned z16[NCG][CLDS][TILE / 2]; // 128 KB packed bf16
    __shared__ __align__(16) float scratch[4096];               // 16 KB (stats tree + yz rounds)
    __shared__ __align__(16) float yzred[M][TILE];              // 4 KB
    __shared__ float sh_s[M];
    __shared__ float sh_ms[2];

    const int tid  = threadIdx.x;
    const int bid  = blockIdx.x;
    const int b    = bid >> 5;
    const int hw0  = (bid & 31) * TILE;
    const int cg   = tid >> 5;
    const int lane = tid & 31;

    const size_t zbase = ((size_t)(b * C + cg * CPG)) * HW + hw0 + lane * 4;

    float4 ym[M];
#pragma unroll
    for (int m = 0; m < M; ++m) ym[m] = make_float4(0.f, 0.f, 0.f, 0.f);
    float su = 0.f, sq = 0.f;
    uint2 zr[CREG];   // channels CLDS..CPG-1, packed bf16 (statically indexed)

    // ---------------- phase A: read z once; stats + yz partials + stash ----
#pragma unroll 8
    for (int ci = 0; ci < CLDS; ++ci) {
        float4 v = *reinterpret_cast<const float4*>(z + zbase + (size_t)ci * HW);
        su += (v.x + v.y) + (v.z + v.w);
        sq += v.x * v.x + v.y * v.y + v.z * v.z + v.w * v.w;
        int c = cg * CPG + ci;
#pragma unroll
        for (int m = 0; m < M; ++m) {
            float w = Wd[m * C + c];
            ym[m].x += w * v.x; ym[m].y += w * v.y;
            ym[m].z += w * v.z; ym[m].w += w * v.w;
        }
        uint2 p; p.x = packbf(v.x, v.y); p.y = packbf(v.z, v.w);
        *reinterpret_cast<uint2*>(&z16[cg][ci][2 * lane]) = p;
    }
#pragma unroll
    for (int ci = 0; ci < CREG; ++ci) {
        float4 v = *reinterpret_cast<const float4*>(z + zbase + (size_t)(ci + CLDS) * HW);
        su += (v.x + v.y) + (v.z + v.w);
        sq += v.x * v.x + v.y * v.y + v.z * v.z + v.w * v.w;
        int c = cg * CPG + CLDS + ci;
#pragma unroll
        for (int m = 0; m < M; ++m) {
            float w = Wd[m * C + c];
            ym[m].x += w * v.x; ym[m].y += w * v.y;
            ym[m].z += w * v.z; ym[m].w += w * v.w;
        }
        zr[ci].x = packbf(v.x, v.y); zr[ci].y = packbf(v.z, v.w);
    }

    // stats block tree-reduce -> ws[bid]
    scratch[tid] = su;
    scratch[2048 + tid] = sq;
    __syncthreads();
    for (int s = TPB / 2; s > 0; s >>= 1) {
        if (tid < s) {
            scratch[tid] += scratch[tid + s];
            scratch[2048 + tid] += scratch[2048 + tid + s];
        }
        __syncthreads();
    }
    if (tid == 0) { ws[bid * 2] = scratch[0]; ws[bid * 2 + 1] = scratch[2048]; }

    // yz cross-cg reduce: 4 rounds of m-pairs through 16 KB scratch
#pragma unroll
    for (int r = 0; r < 4; ++r) {
        __syncthreads();
        *reinterpret_cast<float4*>(&scratch[cg * 256 + lane * 4])       = ym[2 * r];
        *reinterpret_cast<float4*>(&scratch[cg * 256 + 128 + lane * 4]) = ym[2 * r + 1];
        __syncthreads();
        if (tid < 64) {
            int sel = tid >> 5, l2 = tid & 31;
            float4 a = make_float4(0.f, 0.f, 0.f, 0.f);
#pragma unroll
            for (int g = 0; g < NCG; ++g) {
                float4 t = *reinterpret_cast<float4*>(&scratch[g * 256 + sel * 128 + l2 * 4]);
                a.x += t.x; a.y += t.y; a.z += t.z; a.w += t.w;
            }
            *reinterpret_cast<float4*>(&yzred[2 * r + sel][l2 * 4]) = a;
        }
    }

    cooperative_groups::this_grid().sync();

    // ---------------- phase B: finalize scalars, apply output --------------
    {
        int w = tid >> 6, l = tid & 63;
        float sm = 0.f;                       // s[m=w] = sum_c W[w,c]
#pragma unroll
        for (int k = 0; k < C / 64; ++k) sm += Wd[w * C + k * 64 + l];
#pragma unroll
        for (int o = 32; o > 0; o >>= 1) sm += __shfl_down(sm, o);
        if (l == 0) sh_s[w] = sm;
        if (w == 0) {                         // mu/istd for batch b
            float pu = 0.f, pq = 0.f;
            if (l < 32) {
                pu = ws[(b * 32 + l) * 2];
                pq = ws[(b * 32 + l) * 2 + 1];
            }
#pragma unroll
            for (int o = 16; o > 0; o >>= 1) {
                pu += __shfl_down(pu, o);
                pq += __shfl_down(pq, o);
            }
            if (l == 0) {
                const float invN = 1.0f / (float)(C * HW);
                float mu  = pu * invN;
                float var = pq * invN - mu * mu;
                sh_ms[0] = mu;
                sh_ms[1] = 1.0f / sqrtf(var + EPS);
            }
        }
    }
    __syncthreads();
    const float mu = sh_ms[0], istd = sh_ms[1];

    float4 y4[M];
#pragma unroll
    for (int m = 0; m < M; ++m) {
        float4 t = *reinterpret_cast<float4*>(&yzred[m][lane * 4]);
        float off = mu * sh_s[m];
        y4[m].x = istd * (t.x - off);
        y4[m].y = istd * (t.y - off);
        y4[m].z = istd * (t.z - off);
        y4[m].w = istd * (t.w - off);
    }

#pragma unroll 8
    for (int ci = 0; ci < CLDS; ++ci) {
        uint2 p = *reinterpret_cast<uint2*>(&z16[cg][ci][2 * lane]);
        float v0 = bflo(p.x), v1 = bfhi(p.x), v2 = bflo(p.y), v3 = bfhi(p.y);
        int c = cg * CPG + ci;
        float r0 = 0.f, r1 = 0.f, r2 = 0.f, r3 = 0.f;
#pragma unroll
        for (int m = 0; m < M; ++m) {
            float w = Wd[m * C + c];
            r0 += w * y4[m].x; r1 += w * y4[m].y;
            r2 += w * y4[m].z; r3 += w * y4[m].w;
        }
        floatx4 o;
        o.x = v0 + GAIN * r0; o.y = v1 + GAIN * r1;
        o.z = v2 + GAIN * r2; o.w = v3 + GAIN * r3;
        __builtin_nontemporal_store(o, reinterpret_cast<floatx4*>(out + zbase + (size_t)ci * HW));
    }
#pragma unroll
    for (int ci = 0; ci < CREG; ++ci) {
        uint2 p = zr[ci];
        float v0 = bflo(p.x), v1 = bfhi(p.x), v2 = bflo(p.y), v3 = bfhi(p.y);
        int c = cg * CPG + CLDS + ci;
        float r0 = 0.f, r1 = 0.f, r2 = 0.f, r3 = 0.f;
#pragma unroll
        for (int m = 0; m < M; ++m) {
            float w = Wd[m * C + c];
            r0 += w * y4[m].x; r1 += w * y4[m].y;
            r2 += w * y4[m].z; r3 += w * y4[m].w;
        }
        floatx4 o;
        o.x = v0 + GAIN * r0; o.y = v1 + GAIN * r1;
        o.z = v2 + GAIN * r2; o.w = v3 + GAIN * r3;
        __builtin_nontemporal_store(o, reinterpret_cast<floatx4*>(out + zbase + (size_t)(ci + CLDS) * HW));
    }
}

extern "C" void kernel_launch(void* const* d_in, const int* in_sizes, int n_in,
                              void* d_out, int out_size, void* d_ws, size_t ws_size,
                              hipStream_t stream) {
    const float* z  = (const float*)d_in[0];   // (8,1024,64,64) fp32
    const float* Wd = (const float*)d_in[1];   // (8,1024) fp32
    float* out = (float*)d_out;
    float* ws  = (float*)d_ws;                 // 2 KB stat partials

    void* args[] = { (void*)&z, (void*)&Wd, (void*)&out, (void*)&ws };
    hipLaunchCooperativeKernel((const void*)fused, dim3(B * NTILE), dim3(TPB),
                               args, 0, stream);
}

// Round 9
// 122.341 us; speedup vs baseline: 1.3545x; 1.3545x over previous
//
#include <hip/hip_runtime.h>
#include <hip/hip_cooperative_groups.h>
#include <math.h>

#define B    8
#define C    1024
#define M    8
#define HW   4096
#define EPS  1e-6f
#define GAIN 0.3f

#define TPB   512         // 8 waves
#define TILE  128         // hw per block
#define NTILE 32          // HW/TILE; grid = B*NTILE = 256 (1 block/CU, proven coop size)
#define NG    16          // channel groups per block
#define CPG   64          // channels per group (NG*CPG = C)

typedef float floatx4 __attribute__((ext_vector_type(4)));

// ws: [256][2] stat partials (su, sq) = 2 KB
__global__ __launch_bounds__(TPB, 2) void fused(const float* __restrict__ z,
                                                const float* __restrict__ Wd,
                                                float* __restrict__ out,
                                                float* __restrict__ ws) {
    // LDS: 64 + 4 + 4 KB = 72.2 KB -> 1 block/CU
    __shared__ __align__(16) float4 scr[NG][M][32];   // cross-group yz exchange
    __shared__ __align__(16) float4 yzacc[M][32];     // block's reduced yz
    __shared__ float sred[2 * TPB];                   // stats tree
    __shared__ float sh_s[M];
    __shared__ float sh_ms[2];

    const int tid = threadIdx.x;
    const int bid = blockIdx.x;
    const int b   = bid >> 5;          // batch
    const int t   = bid & 31;          // hw tile
    const int g   = tid >> 5;          // channel group 0..15
    const int s   = tid & 31;          // float4 slot within 128 hw
    const int hwb = t * TILE + s * 4;
    const size_t zoff = ((size_t)(b * C + g * CPG)) * HW + hwb;

    // ---------------- phase A: read z once -> stats + fully-reduced yz -----
    float4 ym[M];
#pragma unroll
    for (int m = 0; m < M; ++m) ym[m] = make_float4(0.f, 0.f, 0.f, 0.f);
    float su = 0.f, sq = 0.f;

#pragma unroll 8
    for (int ci = 0; ci < CPG; ++ci) {
        float4 v = *reinterpret_cast<const float4*>(z + zoff + (size_t)ci * HW);
        su += (v.x + v.y) + (v.z + v.w);
        sq += v.x * v.x + v.y * v.y + v.z * v.z + v.w * v.w;
        int c = g * CPG + ci;
#pragma unroll
        for (int m = 0; m < M; ++m) {
            float w = Wd[m * C + c];
            ym[m].x += w * v.x; ym[m].y += w * v.y;
            ym[m].z += w * v.z; ym[m].w += w * v.w;
        }
    }

#pragma unroll
    for (int m = 0; m < M; ++m) scr[g][m][s] = ym[m];
    sred[tid] = su;
    sred[TPB + tid] = sq;
    __syncthreads();

    if (tid < 256) {
        // cross-group yz reduce: thread (m2, s2) sums 16 group partials
        int m2 = tid >> 5, s2 = tid & 31;
        float4 a = make_float4(0.f, 0.f, 0.f, 0.f);
#pragma unroll
        for (int g2 = 0; g2 < NG; ++g2) {
            float4 v = scr[g2][m2][s2];
            a.x += v.x; a.y += v.y; a.z += v.z; a.w += v.w;
        }
        yzacc[m2][s2] = a;
        // first stats tree step folded in
        sred[tid] += sred[tid + 256];
        sred[TPB + tid] += sred[TPB + tid + 256];
    }
    __syncthreads();
    for (int r = 128; r > 0; r >>= 1) {
        if (tid < r) {
            sred[tid] += sred[tid + r];
            sred[TPB + tid] += sred[TPB + tid + r];
        }
        __syncthreads();
    }
    if (tid == 0) {
        ws[bid * 2]     = sred[0];
        ws[bid * 2 + 1] = sred[TPB];
    }

    cooperative_groups::this_grid().sync();

    // ---------------- phase B: finalize scalars, normalize, apply ----------
    {
        int wv = tid >> 6, l = tid & 63;
        float sm = 0.f;                       // s[m = wv] = sum_c W[wv,c]
#pragma unroll
        for (int k = 0; k < C / 64; ++k) sm += Wd[wv * C + k * 64 + l];
#pragma unroll
        for (int o = 32; o > 0; o >>= 1) sm += __shfl_down(sm, o);
        if (l == 0) sh_s[wv] = sm;
        if (wv == 0) {                        // mu/istd for batch b: 32 partials
            float pu = 0.f, pq = 0.f;
            if (l < 32) {
                pu = ws[(b * 32 + l) * 2];
                pq = ws[(b * 32 + l) * 2 + 1];
            }
#pragma unroll
            for (int o = 16; o > 0; o >>= 1) {
                pu += __shfl_down(pu, o);
                pq += __shfl_down(pq, o);
            }
            if (l == 0) {
                const float invN = 1.0f / (float)(C * HW);
                float mu  = pu * invN;
                float var = pq * invN - mu * mu;
                sh_ms[0] = mu;
                sh_ms[1] = 1.0f / sqrtf(var + EPS);
            }
        }
    }
    __syncthreads();
    const float mu = sh_ms[0], istd = sh_ms[1];

    float4 y4[M];
#pragma unroll
    for (int m = 0; m < M; ++m) {
        float4 v  = yzacc[m][s];              // broadcast across groups
        float off = mu * sh_s[m];
        y4[m].x = istd * (v.x - off);
        y4[m].y = istd * (v.y - off);
        y4[m].z = istd * (v.z - off);
        y4[m].w = istd * (v.w - off);
    }

    // descending ci: tail channels of phase A may still be L2-warm
#pragma unroll 4
    for (int ci = CPG - 1; ci >= 0; --ci) {
        float4 v = *reinterpret_cast<const float4*>(z + zoff + (size_t)ci * HW);
        int c = g * CPG + ci;
        float r0 = 0.f, r1 = 0.f, r2 = 0.f, r3 = 0.f;
#pragma unroll
        for (int m = 0; m < M; ++m) {
            float w = Wd[m * C + c];
            r0 += w * y4[m].x; r1 += w * y4[m].y;
            r2 += w * y4[m].z; r3 += w * y4[m].w;
        }
        floatx4 o;
        o.x = v.x + GAIN * r0; o.y = v.y + GAIN * r1;
        o.z = v.z + GAIN * r2; o.w = v.w + GAIN * r3;
        __builtin_nontemporal_store(o, reinterpret_cast<floatx4*>(out + zoff + (size_t)ci * HW));
    }
}

extern "C" void kernel_launch(void* const* d_in, const int* in_sizes, int n_in,
                              void* d_out, int out_size, void* d_ws, size_t ws_size,
                              hipStream_t stream) {
    const float* z  = (const float*)d_in[0];   // (8,1024,64,64) fp32
    const float* Wd = (const float*)d_in[1];   // (8,1024) fp32
    float* out = (float*)d_out;
    float* ws  = (float*)d_ws;                 // 2 KB stat partials

    void* args[] = { (void*)&z, (void*)&Wd, (void*)&out, (void*)&ws };
    hipLaunchCooperativeKernel((const void*)fused, dim3(B * NTILE), dim3(TPB),
                               args, 0, stream);
}

// Round 10
// 73.675 us; speedup vs baseline: 2.2493x; 1.6606x over previous
//
#include <hip/hip_runtime.h>
#include <math.h>

#define B    8
#define C    1024
#define M    8
#define HW   4096
#define EPS  1e-6f
#define GAIN 0.3f
#define TPB  256

typedef float floatx4 __attribute__((ext_vector_type(4)));

// ---- K1 geometry: grid = B*NT1*NC1 = 1024, block = 256hw x 128ch ----------
#define NT1  16
#define NC1  8
#define HWT1 256          // 64 float4 slots
#define CCH1 128          // 4 h-groups x 32 ch

// ---- K3 geometry: grid = B*NT3*NC3 = 1024, block = 512hw x 64ch -----------
#define NT3  8
#define NC3  16
#define HWT3 512          // 128 float4 slots
#define CCH3 64           // 2 h-groups x 32 ch

// ws layout (float offsets)
#define OFF_YZP   0                          // [B][NC1][M][HW] = 2,097,152
#define OFF_Y     (OFF_YZP + B*NC1*M*HW)     // [B][M][HW]      = 262,144
#define OFF_STATP (OFF_Y + B*M*HW)           // [1024][2]       = 2048

// ---------------- K1: partial stats + partial yz = W @ z -------------------
__global__ __launch_bounds__(TPB) void k1_partial(const float* __restrict__ z,
                                                  const float* __restrict__ Wd,
                                                  float* __restrict__ ws) {
    const int bid = blockIdx.x;
    const int nc  = bid & 7;
    const int t   = (bid >> 3) & 15;
    const int b   = bid >> 7;
    const int tid = threadIdx.x;
    const int h   = tid >> 6;          // 0..3 (wave-uniform)
    const int s   = tid & 63;          // float4 slot
    const int hw  = t * HWT1 + s * 4;
    const int c0  = nc * CCH1 + h * 32;

    __shared__ __align__(16) float4 scr[3][M][64];   // 24 KB: h=1..3 partial ym
    __shared__ float sred[2 * TPB];                  // 2 KB: stats tree

    float4 ym[M];
#pragma unroll
    for (int m = 0; m < M; ++m) ym[m] = make_float4(0.f, 0.f, 0.f, 0.f);
    float su = 0.f, sq = 0.f;

    const float* zp = z + ((size_t)(b * C + c0)) * HW + hw;
#pragma unroll 4
    for (int ci = 0; ci < 32; ++ci) {
        float4 v = *reinterpret_cast<const float4*>(zp + (size_t)ci * HW);
        su += (v.x + v.y) + (v.z + v.w);
        sq += v.x * v.x + v.y * v.y + v.z * v.z + v.w * v.w;
        int c = c0 + ci;
#pragma unroll
        for (int m = 0; m < M; ++m) {
            float w = Wd[m * C + c];               // wave-uniform -> s_load
            ym[m].x += w * v.x; ym[m].y += w * v.y;
            ym[m].z += w * v.z; ym[m].w += w * v.w;
        }
    }

    // combine 4 h-groups in LDS; h=0 threads write the block's yz partial
    if (h > 0) {
#pragma unroll
        for (int m = 0; m < M; ++m) scr[h - 1][m][s] = ym[m];
    }
    sred[tid] = su;
    sred[TPB + tid] = sq;
    __syncthreads();
    if (h == 0) {
        float* yzp = ws + OFF_YZP + ((size_t)((b * NC1 + nc) * M)) * HW + hw;
#pragma unroll
        for (int m = 0; m < M; ++m) {
            float4 a = ym[m];
            float4 p1 = scr[0][m][s], p2 = scr[1][m][s], p3 = scr[2][m][s];
            a.x += (p1.x + p2.x) + p3.x;
            a.y += (p1.y + p2.y) + p3.y;
            a.z += (p1.z + p2.z) + p3.z;
            a.w += (p1.w + p2.w) + p3.w;
            *reinterpret_cast<float4*>(yzp + (size_t)m * HW) = a;
        }
    }
    // stats block tree-reduce -> statp[bid]
    for (int r = TPB / 2; r > 0; r >>= 1) {
        if (tid < r) {
            sred[tid] += sred[tid + r];
            sred[TPB + tid] += sred[TPB + tid + r];
        }
        __syncthreads();
    }
    if (tid == 0) {
        ws[OFF_STATP + bid * 2]     = sred[0];
        ws[OFF_STATP + bid * 2 + 1] = sred[TPB];
    }
}

// ---- K2: finalize stats in-block, reduce yz partials -> normalized y ------
// grid 256: b = bid>>5, m = (bid>>2)&7, hwblk = bid&3
__global__ __launch_bounds__(TPB) void k2_reduce_y(const float* __restrict__ Wd,
                                                   float* __restrict__ ws) {
    const int bid   = blockIdx.x;
    const int b     = bid >> 5;
    const int m     = (bid >> 2) & 7;
    const int hwblk = bid & 3;
    const int tid   = threadIdx.x;
    const int wv    = tid >> 6;
    const int l     = tid & 63;
    const int hw    = hwblk * 1024 + tid * 4;

    __shared__ float sh[3];   // mu, istd, s_m

    if (wv == 0) {
        // stats for batch b: 128 partials (= NT1*NC1), 2 per lane
        const float* sp = ws + OFF_STATP + (size_t)(b * 128 + l) * 2;
        float su = sp[0] + sp[128];
        float sq = sp[1] + sp[129];
#pragma unroll
        for (int o = 32; o > 0; o >>= 1) {
            su += __shfl_down(su, o);
            sq += __shfl_down(sq, o);
        }
        if (l == 0) {
            const float invN = 1.0f / (float)(C * HW);
            float mu  = su * invN;
            float var = sq * invN - mu * mu;
            sh[0] = mu;
            sh[1] = 1.0f / sqrtf(var + EPS);
        }
    } else if (wv == 1) {
        float sm = 0.f;                        // s[m] = sum_c W[m,c]
#pragma unroll
        for (int k = 0; k < C / 64; ++k) sm += Wd[m * C + k * 64 + l];
#pragma unroll
        for (int o = 32; o > 0; o >>= 1) sm += __shfl_down(sm, o);
        if (l == 0) sh[2] = sm;
    }
    __syncthreads();
    const float istd = sh[1];
    const float off  = sh[0] * sh[2];

    float4 acc = make_float4(0.f, 0.f, 0.f, 0.f);
    const float* p = ws + OFF_YZP + ((size_t)(b * NC1 * M + m)) * HW + hw;
#pragma unroll
    for (int ncp = 0; ncp < NC1; ++ncp) {
        float4 v = *reinterpret_cast<const float4*>(p + (size_t)(ncp * M) * HW);
        acc.x += v.x; acc.y += v.y; acc.z += v.z; acc.w += v.w;
    }
    float4 y;
    y.x = istd * (acc.x - off);
    y.y = istd * (acc.y - off);
    y.z = istd * (acc.z - off);
    y.w = istd * (acc.w - off);
    *reinterpret_cast<float4*>(ws + OFF_Y + ((size_t)(b * M + m)) * HW + hw) = y;
}

// ---------------- K3: out = z + GAIN * W^T y -------------------------------
// Reversed block order: first-dispatched blocks touch the z K1 read last
// (best chance of L3 residency). nt-stores keep out from evicting z.
__global__ __launch_bounds__(TPB) void k3_apply(const float* __restrict__ z,
                                                const float* __restrict__ Wd,
                                                const float* __restrict__ ws,
                                                float* __restrict__ out) {
    const int rbid = (B * NT3 * NC3 - 1) - blockIdx.x;
    const int nc  = rbid & 15;
    const int t   = (rbid >> 4) & 7;
    const int b   = rbid >> 7;
    const int tid = threadIdx.x;
    const int h   = tid >> 7;          // 0..1 (wave-uniform)
    const int s   = tid & 127;         // float4 slot
    const int hw  = t * HWT3 + s * 4;
    const int c0  = nc * CCH3 + h * 32;

    // normalized y[m] at this thread's 4 hw positions: 32 VGPRs
    float4 y4[M];
    const float* yp = ws + OFF_Y + (size_t)b * M * HW + hw;
#pragma unroll
    for (int m = 0; m < M; ++m)
        y4[m] = *reinterpret_cast<const float4*>(yp + (size_t)m * HW);

    const float* zp = z + ((size_t)(b * C + c0)) * HW + hw;
    float* op = out + ((size_t)(b * C + c0)) * HW + hw;
#pragma unroll 4
    for (int ci = 0; ci < 32; ++ci) {
        float4 v = *reinterpret_cast<const float4*>(zp + (size_t)ci * HW);
        int c = c0 + ci;
        float r0 = 0.f, r1 = 0.f, r2 = 0.f, r3 = 0.f;
#pragma unroll
        for (int m = 0; m < M; ++m) {
            float w = Wd[m * C + c];               // wave-uniform -> s_load
            r0 += w * y4[m].x; r1 += w * y4[m].y;
            r2 += w * y4[m].z; r3 += w * y4[m].w;
        }
        floatx4 o;
        o.x = v.x + GAIN * r0; o.y = v.y + GAIN * r1;
        o.z = v.z + GAIN * r2; o.w = v.w + GAIN * r3;
        __builtin_nontemporal_store(o, reinterpret_cast<floatx4*>(op + (size_t)ci * HW));
    }
}

extern "C" void kernel_launch(void* const* d_in, const int* in_sizes, int n_in,
                              void* d_out, int out_size, void* d_ws, size_t ws_size,
                              hipStream_t stream) {
    const float* z  = (const float*)d_in[0];   // (8,1024,64,64) fp32
    const float* Wd = (const float*)d_in[1];   // (8,1024) fp32
    float* out = (float*)d_out;
    float* ws  = (float*)d_ws;                 // ~9.4 MB

    dim3 blk(TPB);
    k1_partial<<<dim3(B * NT1 * NC1), blk, 0, stream>>>(z, Wd, ws);
    k2_reduce_y<<<dim3(B * M * 4), blk, 0, stream>>>(Wd, ws);
    k3_apply<<<dim3(B * NT3 * NC3), blk, 0, stream>>>(z, Wd, ws, out);
}